// Round 1
// baseline (250.965 us; speedup 1.0000x reference)
//
#include <hip/hip_runtime.h>
#include <cstdint>
#include <cstddef>

#define NTH 256
#define NGT 128
#define BATCH 16
#define NC 80
#define G 16                  // GTs per block
#define NCHUNK (NGT / G)      // 8
#define HW0 25600
#define HW1 6400
#define HW2 1600
#define SL0 4                 // hw slices for level 0

#define NGRP0 (BATCH * NCHUNK)            // 128 level-0 (b,chunk) groups
#define GRID0 (BATCH * SL0 * NCHUNK)      // 512 level-0 blocks
#define GRID1 (BATCH * NCHUNK)            // 128
#define GRID2 (BATCH * NCHUNK)            // 128
#define GRID  (GRID0 + GRID1 + GRID2)     // 768
#define NLOSS (3 * NGRP0)                 // 384 loss-writer partial triples

// ws layout (bytes)
#define PART_OFF   0
#define PART_BYTES (NGRP0 * G * SL0 * 8)          // 65536: lvl0 slice keys
#define PARTL_OFF  PART_BYTES
#define PARTL_BYTES (NLOSS * 3 * 4)               // 4608
#define CTR_OFF    (PARTL_OFF + PARTL_BYTES)      // 70144
#define NCTR       (NGRP0 + 1)                    // 128 group ctrs + 1 global
#define WS_NEEDED  ((size_t)CTR_OFF + (size_t)NCTR * 4)

__device__ __forceinline__ unsigned long long umin64(unsigned long long a, unsigned long long b) {
    return a < b ? a : b;
}

// Counters live in poisoned workspace -> must be zeroed before the fused kernel.
__global__ __launch_bounds__(NTH) void zero_kernel(unsigned int* __restrict__ ctrs) {
    if (threadIdx.x < NCTR) ctrs[threadIdx.x] = 0u;
}

// u64 key (d2 bits << 32 | idx): min == min-d2 with first-index tie-break,
// exactly matching jnp.argmin (d2 >= 0 so float bits order == integer order).
#define EVAL(px, py, idx_) do {                                                   \
    _Pragma("unroll")                                                             \
    for (int g = 0; g < G; ++g) {                                                 \
        float dx = gx[g] - (px), dy = gy[g] - (py);                               \
        float d2 = dx * dx + dy * dy;                                             \
        unsigned long long key =                                                  \
            ((unsigned long long)__float_as_uint(d2) << 32) | (unsigned)(idx_);   \
        kmin[g] = umin64(kmin[g], key);                                           \
    } } while (0)

// One kernel: scan (argmin over positions) + loss (softmax/L1 for this block's
// 16 GTs) + final reduce (by the globally-last loss-writing block).
// Level 1/2: block holds its full keys -> loss inline, no global round-trip.
// Level 0: 4 slice blocks per (b,chunk) group combine through `part` with a
// per-group completion counter (release: store+fence+atomic; acquire: fence).
__global__ __launch_bounds__(NTH) void fused_kernel(
    const float* __restrict__ cls0, const float* __restrict__ cls1, const float* __restrict__ cls2,
    const float* __restrict__ reg0, const float* __restrict__ reg1, const float* __restrict__ reg2,
    const float* __restrict__ gt_boxes, const int* __restrict__ gt_labels,
    unsigned long long* __restrict__ part, float* __restrict__ partl,
    unsigned int* __restrict__ ctrs, float* __restrict__ out)
{
    __shared__ unsigned long long red[G][4];
    __shared__ unsigned long long keyS[G];
    __shared__ float tr[3][4];
    __shared__ float fm[3][4];
    __shared__ int flag;   // lvl0: am I the last slice block of my group?
    __shared__ int lastG;  // am I the last loss-writing block overall?

    const int x = blockIdx.x;
    int lvl, b, slice, chunk, HW, nsl;
    const float* reg;
    const float* cls;
    if (x < GRID0) {
        lvl = 0; b = x / (SL0 * NCHUNK);
        int r = x % (SL0 * NCHUNK);
        slice = r / NCHUNK; chunk = r % NCHUNK;
        HW = HW0; nsl = SL0; reg = reg0; cls = cls0;
    } else if (x < GRID0 + GRID1) {
        int y = x - GRID0;
        lvl = 1; b = y / NCHUNK; chunk = y % NCHUNK; slice = 0;
        HW = HW1; nsl = 1; reg = reg1; cls = cls1;
    } else {
        int y = x - GRID0 - GRID1;
        lvl = 2; b = y / NCHUNK; chunk = y % NCHUNK; slice = 0;
        HW = HW2; nsl = 1; reg = reg2; cls = cls2;
    }

    const int seg = HW / nsl;
    const int e0 = slice * seg, e1 = e0 + seg;
    const int tid = threadIdx.x, wave = tid >> 6, lane = tid & 63;
    const int n0 = chunk * G;

    // ---- scan phase ----
    float gx[G], gy[G];
#pragma unroll
    for (int g = 0; g < G; ++g) {
        const float* gb = gt_boxes + (size_t)(b * NGT + n0 + g) * 4;
        gx[g] = gb[0]; gy[g] = gb[1];
    }

    unsigned long long kmin[G];
#pragma unroll
    for (int g = 0; g < G; ++g) kmin[g] = ~0ull;

    // raw reg rows: 16 B/lane fully coalesced; chunk re-reads hit L2/L3.
    const float4* rows = reinterpret_cast<const float4*>(reg) + (size_t)b * HW;
    for (int i = e0 + tid; i < e1; i += NTH) {
        float4 p = rows[i];
        EVAL(p.x, p.y, i);
    }

#pragma unroll
    for (int g = 0; g < G; ++g) {
#pragma unroll
        for (int off = 32; off >= 1; off >>= 1) {
            unsigned long long o = __shfl_down(kmin[g], off, 64);
            kmin[g] = umin64(kmin[g], o);
        }
    }
    if (lane == 0) {
#pragma unroll
        for (int g = 0; g < G; ++g) red[g][wave] = kmin[g];
    }
    __syncthreads();

    const int wslot = lvl * NGRP0 + b * NCHUNK + chunk;   // loss-writer slot

    if (lvl == 0) {
        const int grp = b * NCHUNK + chunk;
        if (tid < G) {
            unsigned long long kfin = umin64(umin64(red[tid][0], red[tid][1]),
                                             umin64(red[tid][2], red[tid][3]));
            part[((size_t)grp * G + tid) * SL0 + slice] = kfin;
            __threadfence();   // release this thread's key store device-wide
        }
        __syncthreads();
        if (tid == 0) flag = (atomicAdd(&ctrs[grp], 1u) == SL0 - 1) ? 1 : 0;
        __syncthreads();
        if (!flag) return;               // not the last slice block of the group
        __threadfence();                 // acquire other slice blocks' stores
        if (tid < G) {
            const unsigned long long* p = part + ((size_t)grp * G + tid) * SL0;
            keyS[tid] = umin64(umin64(p[0], p[1]), umin64(p[2], p[3]));
        }
        __syncthreads();
    } else {
        if (tid < G) {
            keyS[tid] = umin64(umin64(red[tid][0], red[tid][1]),
                               umin64(red[tid][2], red[tid][3]));
        }
        __syncthreads();
    }

    // ---- loss phase: this block owns GTs [n0, n0+16); wave w -> 4 GTs ----
    float ceA = 0.0f, l1A = 0.0f, wA = 0.0f;
#pragma unroll
    for (int sub = 0; sub < 4; ++sub) {
        const int nl = wave * 4 + sub;
        const unsigned long long key = keyS[nl];
        const float d2min = __uint_as_float((unsigned)(key >> 32));
        if (d2min < 6.25f) {             // sqrt(d2) < 2.5; wave-uniform branch
            const int match = (int)(unsigned)(key & 0xffffffffu);
            const int n = n0 + nl;
            const float* c = cls + ((size_t)b * HW + match) * NC;
            // 80-class log-softmax across the wave
            float x1 = c[lane];
            float x2 = (lane < NC - 64) ? c[64 + lane] : -INFINITY;
            float mx = fmaxf(x1, x2);
#pragma unroll
            for (int off = 32; off >= 1; off >>= 1) mx = fmaxf(mx, __shfl_xor(mx, off, 64));
            float sden = expf(x1 - mx) + ((lane < NC - 64) ? expf(x2 - mx) : 0.0f);
#pragma unroll
            for (int off = 32; off >= 1; off >>= 1) sden += __shfl_xor(sden, off, 64);
            if (lane == 0) {
                const int label = gt_labels[b * NGT + n];
                const float xlab = c[label];
                ceA += -(xlab - mx - logf(sden));
                const float* gb = gt_boxes + (size_t)(b * NGT + n) * 4;
                const float* gr = reg + ((size_t)b * HW + match) * 4;
                l1A += fabsf(gr[0] - gb[0]) + fabsf(gr[1] - gb[1]) +
                       fabsf(gr[2] - gb[2]) + fabsf(gr[3] - gb[3]);
                wA += 1.0f;
            }
        }
    }

    if (lane == 0) { tr[0][wave] = ceA; tr[1][wave] = l1A; tr[2][wave] = wA; }
    __syncthreads();
    if (tid == 0) {
        float* o = partl + (size_t)wslot * 3;
        o[0] = tr[0][0] + tr[0][1] + tr[0][2] + tr[0][3];
        o[1] = tr[1][0] + tr[1][1] + tr[1][2] + tr[1][3];
        o[2] = tr[2][0] + tr[2][1] + tr[2][2] + tr[2][3];
        __threadfence();   // release the triple before announcing completion
        lastG = (atomicAdd(&ctrs[NGRP0], 1u) == NLOSS - 1) ? 1 : 0;
    }
    __syncthreads();
    if (!lastG) return;

    // ---- final reduce: deterministic tree over 384 triples ----
    __threadfence();       // acquire all other blocks' triples
    float ce = 0.0f, l1 = 0.0f, w = 0.0f;
    for (int i = tid; i < NLOSS; i += NTH) {
        const float* o = partl + (size_t)i * 3;
        ce += o[0]; l1 += o[1]; w += o[2];
    }
#pragma unroll
    for (int off = 32; off >= 1; off >>= 1) {
        ce += __shfl_xor(ce, off, 64);
        l1 += __shfl_xor(l1, off, 64);
        w  += __shfl_xor(w,  off, 64);
    }
    if (lane == 0) { fm[0][wave] = ce; fm[1][wave] = l1; fm[2][wave] = w; }
    __syncthreads();
    if (tid == 0) {
        float tce = fm[0][0] + fm[0][1] + fm[0][2] + fm[0][3];
        float tl1 = fm[1][0] + fm[1][1] + fm[1][2] + fm[1][3];
        float tw  = fm[2][0] + fm[2][1] + fm[2][2] + fm[2][3];
        float denom = fmaxf(tw, 1.0f);
        out[0] = tce / denom;
        out[1] = tl1 / denom;
        out[2] = tw;
    }
}

extern "C" void kernel_launch(void* const* d_in, const int* in_sizes, int n_in,
                              void* d_out, int out_size, void* d_ws, size_t ws_size,
                              hipStream_t stream) {
    // Map inputs BY SIZE (dict order interleaves cls/reg; all sizes distinct).
    const float* cls0 = nullptr; const float* cls1 = nullptr; const float* cls2 = nullptr;
    const float* reg0 = nullptr; const float* reg1 = nullptr; const float* reg2 = nullptr;
    const float* gt_boxes = nullptr; const int* gt_labels = nullptr;
    for (int i = 0; i < n_in; ++i) {
        switch (in_sizes[i]) {
            case BATCH * HW0 * NC: cls0 = (const float*)d_in[i]; break;
            case BATCH * HW1 * NC: cls1 = (const float*)d_in[i]; break;
            case BATCH * HW2 * NC: cls2 = (const float*)d_in[i]; break;
            case BATCH * HW0 * 4:  reg0 = (const float*)d_in[i]; break;
            case BATCH * HW1 * 4:  reg1 = (const float*)d_in[i]; break;
            case BATCH * HW2 * 4:  reg2 = (const float*)d_in[i]; break;
            case BATCH * NGT * 4:  gt_boxes = (const float*)d_in[i]; break;
            case BATCH * NGT:      gt_labels = (const int*)d_in[i]; break;
            default: break;
        }
    }

    char* ws = (char*)d_ws;
    unsigned long long* part = (unsigned long long*)(ws + PART_OFF);
    float* partl             = (float*)(ws + PARTL_OFF);
    unsigned int* ctrs       = (unsigned int*)(ws + CTR_OFF);

    zero_kernel<<<1, NTH, 0, stream>>>(ctrs);
    fused_kernel<<<GRID, NTH, 0, stream>>>(
        cls0, cls1, cls2, reg0, reg1, reg2, gt_boxes, gt_labels,
        part, partl, ctrs, (float*)d_out);
}

// Round 2
// 216.710 us; speedup vs baseline: 1.1581x; 1.1581x over previous
//
#include <hip/hip_runtime.h>
#include <cstdint>
#include <cstddef>

#define NTH 256
#define NGT 128
#define BATCH 16
#define NC 80
#define G 16                  // GTs per scan block
#define NCHUNK (NGT / G)      // 8
#define HW0 25600
#define HW1 6400
#define HW2 1600
#define SL0 4                 // hw slices for level 0
#define MAXSL 4
#define NLOSS_BLK (3 * BATCH * NGT / 4)   // 1536 loss blocks (4 GTs each)

// ws layout (bytes) — no pack buffers, no counters (nothing needs zeroing:
// every part/partl slot is written before it is read).
#define PART_OFF  0
#define PART_BYTES (3 * BATCH * NGT * MAXSL * 8)   // 196608
#define PARTL_OFF PART_BYTES
#define PARTL_BYTES (NLOSS_BLK * 3 * sizeof(float))
#define WS_NEEDED ((size_t)PARTL_OFF + (size_t)PARTL_BYTES)

__device__ __forceinline__ unsigned long long umin64(unsigned long long a, unsigned long long b) {
    return a < b ? a : b;
}

// u64 key (d2 bits << 32 | idx): min == min-d2 with first-index tie-break,
// exactly matching jnp.argmin (d2 >= 0 so float-bit order == integer order).
#define EVAL(px, py, idx_) do {                                                   \
    _Pragma("unroll")                                                             \
    for (int g = 0; g < G; ++g) {                                                 \
        float dx = gx[g] - (px), dy = gy[g] - (py);                               \
        float d2 = dx * dx + dy * dy;                                             \
        unsigned long long key =                                                  \
            ((unsigned long long)__float_as_uint(d2) << 32) | (unsigned)(idx_);   \
        kmin[g] = umin64(kmin[g], key);                                           \
    } } while (0)

// Scan: one block per (level, batch, hw-slice, chunk-of-16-GTs).
// Reads raw reg rows as coalesced float4 (16 B/lane); the 8 chunk blocks that
// share a (b,slice) region re-read L2/L3-resident data (reg total = 8.6 MB).
// NO cross-block sync: partial keys go to `part`, combined by loss_kernel
// after the kernel-boundary (the cheap global sync on this chip — R1's
// per-block agent fences regressed 30 us).
__global__ __launch_bounds__(NTH) void scan_kernel(
    const float* __restrict__ reg0, const float* __restrict__ reg1, const float* __restrict__ reg2,
    const float* __restrict__ gt_boxes,
    unsigned long long* __restrict__ part)
{
    int x = blockIdx.x;
    int lvl, b, slice, chunk, HW, nsl;
    const float* reg;
    if (x < BATCH * SL0 * NCHUNK) {                         // 512 lvl-0 blocks
        lvl = 0; b = x / (SL0 * NCHUNK);
        int r = x % (SL0 * NCHUNK);
        slice = r / NCHUNK; chunk = r % NCHUNK;
        HW = HW0; nsl = SL0; reg = reg0;
    } else if (x < BATCH * SL0 * NCHUNK + BATCH * NCHUNK) { // 128 lvl-1 blocks
        int y = x - BATCH * SL0 * NCHUNK;
        lvl = 1; b = y / NCHUNK; chunk = y % NCHUNK; slice = 0;
        HW = HW1; nsl = 1; reg = reg1;
    } else {                                                // 128 lvl-2 blocks
        int y = x - BATCH * SL0 * NCHUNK - BATCH * NCHUNK;
        lvl = 2; b = y / NCHUNK; chunk = y % NCHUNK; slice = 0;
        HW = HW2; nsl = 1; reg = reg2;
    }

    const int seg = HW / nsl;
    const int e0 = slice * seg, e1 = e0 + seg;
    const int tid = threadIdx.x, wave = tid >> 6, lane = tid & 63;
    const int n0 = chunk * G;

    float gx[G], gy[G];
#pragma unroll
    for (int g = 0; g < G; ++g) {
        const float* gb = gt_boxes + (size_t)(b * NGT + n0 + g) * 4;
        gx[g] = gb[0]; gy[g] = gb[1];
    }

    unsigned long long kmin[G];
#pragma unroll
    for (int g = 0; g < G; ++g) kmin[g] = ~0ull;

    const float4* rows = reinterpret_cast<const float4*>(reg) + (size_t)b * HW;
#pragma unroll 2
    for (int i = e0 + tid; i < e1; i += NTH) {
        float4 p = rows[i];
        EVAL(p.x, p.y, i);
    }

#pragma unroll
    for (int g = 0; g < G; ++g) {
#pragma unroll
        for (int off = 32; off >= 1; off >>= 1) {
            unsigned long long o = __shfl_down(kmin[g], off, 64);
            kmin[g] = umin64(kmin[g], o);
        }
    }

    __shared__ unsigned long long smem[G][4];
    if (lane == 0) {
#pragma unroll
        for (int g = 0; g < G; ++g) smem[g][wave] = kmin[g];
    }
    __syncthreads();

    if (tid < G) {
        unsigned long long key = umin64(umin64(smem[tid][0], smem[tid][1]),
                                        umin64(smem[tid][2], smem[tid][3]));
        part[((size_t)(lvl * BATCH + b) * NGT + n0 + tid) * MAXSL + slice] = key;
    }
}

// Loss: one wave per (level, batch, gt); 4 waves per block. NO ATOMICS —
// block reduces its 4 (ce,l1,w) triples in LDS and writes ONE partial triple
// to a distinct slot. (Old-session R3: 18K same-address atomicAdds serialized
// at ~31 cyc each; this removes them entirely.)
__global__ __launch_bounds__(NTH) void loss_kernel(
    const float* __restrict__ cls0, const float* __restrict__ cls1, const float* __restrict__ cls2,
    const float* __restrict__ reg0, const float* __restrict__ reg1, const float* __restrict__ reg2,
    const float* __restrict__ gt_boxes, const int* __restrict__ gt_labels,
    const unsigned long long* __restrict__ part, float* __restrict__ partl)
{
    const int wave = threadIdx.x >> 6;
    const int lane = threadIdx.x & 63;
    const int gid = blockIdx.x * 4 + wave;     // 0..6143
    const int lvl = gid / (BATCH * NGT);
    const int r = gid % (BATCH * NGT);
    const int b = r / NGT, n = r % NGT;

    const float* cls; const float* reg; int HW, S;
    if (lvl == 0)      { cls = cls0; reg = reg0; HW = HW0; S = SL0; }
    else if (lvl == 1) { cls = cls1; reg = reg1; HW = HW1; S = 1; }
    else               { cls = cls2; reg = reg2; HW = HW2; S = 1; }

    const unsigned long long* p = part + (size_t)gid * MAXSL;
    unsigned long long key = p[0];
    for (int s = 1; s < S; ++s) key = umin64(key, p[s]);

    int match = (int)(unsigned)(key & 0xffffffffu);
    float d2min = __uint_as_float((unsigned)(key >> 32));
    bool valid = d2min < 6.25f;  // sqrt(d2) < 2.5

    const int label = gt_labels[b * NGT + n];
    const float* c = cls + ((size_t)b * HW + match) * NC;

    // 80-class log-softmax across the wave
    float x1 = c[lane];
    float x2 = (lane < NC - 64) ? c[64 + lane] : -INFINITY;
    float mx = fmaxf(x1, x2);
#pragma unroll
    for (int off = 32; off >= 1; off >>= 1) mx = fmaxf(mx, __shfl_xor(mx, off, 64));
    float s = expf(x1 - mx) + ((lane < NC - 64) ? expf(x2 - mx) : 0.0f);
#pragma unroll
    for (int off = 32; off >= 1; off >>= 1) s += __shfl_xor(s, off, 64);

    __shared__ float ce_s[4], l1_s[4], w_s[4];
    if (lane == 0) {
        float ce = 0.0f, l1 = 0.0f, w = 0.0f;
        if (valid) {
            float xlab = c[label];
            ce = -(xlab - mx - logf(s));
            const float* gb = gt_boxes + (size_t)(b * NGT + n) * 4;
            const float* gr = reg + ((size_t)b * HW + match) * 4;
            l1 = fabsf(gr[0] - gb[0]) + fabsf(gr[1] - gb[1]) +
                 fabsf(gr[2] - gb[2]) + fabsf(gr[3] - gb[3]);
            w = 1.0f;
        }
        ce_s[wave] = ce; l1_s[wave] = l1; w_s[wave] = w;
    }
    __syncthreads();

    if (threadIdx.x == 0) {
        float* o = partl + (size_t)blockIdx.x * 3;
        o[0] = ce_s[0] + ce_s[1] + ce_s[2] + ce_s[3];
        o[1] = l1_s[0] + l1_s[1] + l1_s[2] + l1_s[3];
        o[2] = w_s[0] + w_s[1] + w_s[2] + w_s[3];
    }
}

// Deterministic tree reduction of the 1536 partial triples; writes outputs.
__global__ __launch_bounds__(NTH) void finalize_kernel(
    const float* __restrict__ partl, float* __restrict__ out)
{
    const int tid = threadIdx.x, wave = tid >> 6, lane = tid & 63;
    float ce = 0.0f, l1 = 0.0f, w = 0.0f;
    for (int i = tid; i < NLOSS_BLK; i += NTH) {
        ce += partl[(size_t)i * 3 + 0];
        l1 += partl[(size_t)i * 3 + 1];
        w  += partl[(size_t)i * 3 + 2];
    }
#pragma unroll
    for (int off = 32; off >= 1; off >>= 1) {
        ce += __shfl_xor(ce, off, 64);
        l1 += __shfl_xor(l1, off, 64);
        w  += __shfl_xor(w,  off, 64);
    }
    __shared__ float sm[3][4];
    if (lane == 0) { sm[0][wave] = ce; sm[1][wave] = l1; sm[2][wave] = w; }
    __syncthreads();
    if (tid == 0) {
        float tce = sm[0][0] + sm[0][1] + sm[0][2] + sm[0][3];
        float tl1 = sm[1][0] + sm[1][1] + sm[1][2] + sm[1][3];
        float tw  = sm[2][0] + sm[2][1] + sm[2][2] + sm[2][3];
        float denom = fmaxf(tw, 1.0f);
        out[0] = tce / denom;
        out[1] = tl1 / denom;
        out[2] = tw;
    }
}

extern "C" void kernel_launch(void* const* d_in, const int* in_sizes, int n_in,
                              void* d_out, int out_size, void* d_ws, size_t ws_size,
                              hipStream_t stream) {
    // Map inputs BY SIZE (dict order interleaves cls/reg; all sizes distinct).
    const float* cls0 = nullptr; const float* cls1 = nullptr; const float* cls2 = nullptr;
    const float* reg0 = nullptr; const float* reg1 = nullptr; const float* reg2 = nullptr;
    const float* gt_boxes = nullptr; const int* gt_labels = nullptr;
    for (int i = 0; i < n_in; ++i) {
        switch (in_sizes[i]) {
            case BATCH * HW0 * NC: cls0 = (const float*)d_in[i]; break;
            case BATCH * HW1 * NC: cls1 = (const float*)d_in[i]; break;
            case BATCH * HW2 * NC: cls2 = (const float*)d_in[i]; break;
            case BATCH * HW0 * 4:  reg0 = (const float*)d_in[i]; break;
            case BATCH * HW1 * 4:  reg1 = (const float*)d_in[i]; break;
            case BATCH * HW2 * 4:  reg2 = (const float*)d_in[i]; break;
            case BATCH * NGT * 4:  gt_boxes = (const float*)d_in[i]; break;
            case BATCH * NGT:      gt_labels = (const int*)d_in[i]; break;
            default: break;
        }
    }

    char* ws = (char*)d_ws;
    unsigned long long* part = (unsigned long long*)(ws + PART_OFF);
    float* partl             = (float*)(ws + PARTL_OFF);
    const int scan_grid = BATCH * SL0 * NCHUNK + 2 * BATCH * NCHUNK;  // 768

    scan_kernel<<<scan_grid, NTH, 0, stream>>>(
        reg0, reg1, reg2, gt_boxes, part);

    loss_kernel<<<NLOSS_BLK, NTH, 0, stream>>>(
        cls0, cls1, cls2, reg0, reg1, reg2, gt_boxes, gt_labels, part, partl);

    finalize_kernel<<<1, NTH, 0, stream>>>(partl, (float*)d_out);
}